// Round 1
// baseline (179.167 us; speedup 1.0000x reference)
//
#include <hip/hip_runtime.h>

// Reference analysis:
//   x: [8, 16, 320, 320, 2] fp32
//   real/imag = x[...,0], x[...,1]
//   fftshift : roll dims 2,3 (H=320, W=320) by -ceil(n/2) = -160 each
//   ifftshift: roll dims 3,2 by -floor(n/2) = -160 each
//   Even sizes => total roll = -320 === 0 (mod 320) on both spatial dims.
//   stack([real, imag], -1) reconstructs the original interleaved layout.
//   => The entire op is the IDENTITY. Output = input, bit-exact.
//
// Fastest path: a single d2d hipMemcpyAsync on the capture stream
// (explicitly allowed by the harness; graph-capturable).

extern "C" void kernel_launch(void* const* d_in, const int* in_sizes, int n_in,
                              void* d_out, int out_size, void* d_ws, size_t ws_size,
                              hipStream_t stream) {
    (void)n_in; (void)d_ws; (void)ws_size; (void)in_sizes;
    const size_t nbytes = (size_t)out_size * sizeof(float);  // 26,214,400 fp32
    hipMemcpyAsync(d_out, d_in[0], nbytes, hipMemcpyDeviceToDevice, stream);
}

// Round 2
// 176.303 us; speedup vs baseline: 1.0162x; 1.0162x over previous
//
#include <hip/hip_runtime.h>

// Reference analysis (verified bit-exact in R1):
//   x: [8, 16, 320, 320, 2] fp32
//   fftshift(dims 2,3 by -160) then ifftshift(dims 3,2 by -160); H=W=320 even
//   => total roll = -320 === 0 (mod 320) per spatial dim => IDENTITY.
//
// R1 post-mortem: hipMemcpyAsync d2d inside graph capture became an SDMA/blit
// copy node: 179 us = 1.17 TB/s effective, ~5x off the compute-kernel copy
// ceiling (harness's own fillBuffer kernel hits 6.7 TB/s on this chip).
// Fix: explicit float4 copy kernel on the CUs.

__global__ __launch_bounds__(256) void copy_f4(const float4* __restrict__ src,
                                               float4* __restrict__ dst) {
    const size_t i = (size_t)blockIdx.x * blockDim.x + threadIdx.x;
    dst[i] = src[i];
}

extern "C" void kernel_launch(void* const* d_in, const int* in_sizes, int n_in,
                              void* d_out, int out_size, void* d_ws, size_t ws_size,
                              hipStream_t stream) {
    (void)n_in; (void)d_ws; (void)ws_size; (void)in_sizes;
    // 26,214,400 fp32 = 6,553,600 float4 (divisible: out_size % 4 == 0)
    const int n4 = out_size / 4;                 // 6,553,600
    const int block = 256;
    const int grid = n4 / block;                 // 25,600 exactly
    copy_f4<<<grid, block, 0, stream>>>((const float4*)d_in[0], (float4*)d_out);
}

// Round 4
// 172.737 us; speedup vs baseline: 1.0372x; 1.0206x over previous
//
#include <hip/hip_runtime.h>

// Reference analysis (verified bit-exact R1/R2):
//   fftshift + ifftshift on even dims (320,320) => IDENTITY. Output = input.
//
// R2 post-mortem: our copy kernel is <62us (absent from top-5; all slots are
// harness poison fills @62us). dur_us ~176 = ~145us harness reset envelope
// (restore d_in + 400MB poison) + ~33us ours. Squeezing our slice only.
//
// R3 post-mortem: __builtin_nontemporal_* rejects HIP's struct float4 —
// needs a native Clang vector type. Use ext_vector_type(4) float (same
// 16B layout). Same experiment as R2, now compilable.

typedef float v4f __attribute__((ext_vector_type(4)));

__global__ __launch_bounds__(256) void copy_f4x4(const v4f* __restrict__ src,
                                                 v4f* __restrict__ dst,
                                                 int stride /* = total threads */) {
    const int i = blockIdx.x * 256 + threadIdx.x;
    // 4 coalesced 16B accesses per thread, grid-strided passes.
    v4f a = __builtin_nontemporal_load(src + i);
    v4f b = __builtin_nontemporal_load(src + i + stride);
    v4f c = __builtin_nontemporal_load(src + i + 2 * stride);
    v4f d = __builtin_nontemporal_load(src + i + 3 * stride);
    __builtin_nontemporal_store(a, dst + i);
    __builtin_nontemporal_store(b, dst + i + stride);
    __builtin_nontemporal_store(c, dst + i + 2 * stride);
    __builtin_nontemporal_store(d, dst + i + 3 * stride);
}

extern "C" void kernel_launch(void* const* d_in, const int* in_sizes, int n_in,
                              void* d_out, int out_size, void* d_ws, size_t ws_size,
                              hipStream_t stream) {
    (void)n_in; (void)d_ws; (void)ws_size; (void)in_sizes;
    // 26,214,400 fp32 = 6,553,600 v4f; 4 per thread -> 1,638,400 threads
    const int n4 = out_size / 4;
    const int threads = n4 / 4;        // 1,638,400 (exact)
    const int block = 256;
    const int grid = threads / block;  // 6,400 (exact)
    copy_f4x4<<<grid, block, 0, stream>>>((const v4f*)d_in[0], (v4f*)d_out,
                                          threads);
}